// Round 6
// baseline (7784.657 us; speedup 1.0000x reference)
//
#include <hip/hip_runtime.h>

// B=16, N=512, D=512, NI=32, GH=64, H=8, L=2, OUT=128, heads=8
#define B_   16
#define N_   512
#define D_   512
#define NI_  32
#define GH_  64
#define H_   8
#define OUT_ 128
#define NH_  8

#define BND   (B_*N_*D_)     // 4194304
#define BID   (B_*NI_*D_)    // 262144
#define DD    (D_*D_)        // 262144

// blockDim must be 256
__device__ __forceinline__ float block_sum(float v, float* sm){
  #pragma unroll
  for (int o = 32; o; o >>= 1) v += __shfl_down(v, o, 64);
  int lane = threadIdx.x & 63, w = threadIdx.x >> 6;
  __syncthreads();
  if (lane == 0) sm[w] = v;
  __syncthreads();
  return sm[0] + sm[1] + sm[2] + sm[3];
}
__device__ __forceinline__ float block_max(float v, float* sm){
  #pragma unroll
  for (int o = 32; o; o >>= 1) v = fmaxf(v, __shfl_down(v, o, 64));
  int lane = threadIdx.x & 63, w = threadIdx.x >> 6;
  __syncthreads();
  if (lane == 0) sm[w] = v;
  __syncthreads();
  return fmaxf(fmaxf(sm[0], sm[1]), fmaxf(sm[2], sm[3]));
}

// ---------- elementwise (all fp32) ----------
__global__ __launch_bounds__(256) void bcast_k(const float* __restrict__ s, float* __restrict__ d, int n){
  int i = blockIdx.x * 256 + threadIdx.x;
  if (i < n) d[i] = s[i & (NI_*D_ - 1)];
}
__global__ __launch_bounds__(256) void add_relu_k(const float* __restrict__ a, const float* __restrict__ b,
                                                  float* __restrict__ o, int n){
  int i = blockIdx.x * 256 + threadIdx.x;
  if (i < n){ float v = a[i] + b[i]; o[i] = v > 0.0f ? v : 0.0f; }
}
__global__ __launch_bounds__(256) void add_relu_ip_k(float* __restrict__ a, const float* __restrict__ b, int n){
  int i = blockIdx.x * 256 + threadIdx.x;
  if (i < n){ float v = a[i] + b[i]; a[i] = v > 0.0f ? v : 0.0f; }
}
__global__ __launch_bounds__(256) void add_k(const float* __restrict__ a, const float* __restrict__ b,
                                             float* __restrict__ o, int n){
  int i = blockIdx.x * 256 + threadIdx.x;
  if (i < n) o[i] = a[i] + b[i];
}
// gat_W [H,D,GH] -> Wcat [D, H*GH] (head-major concat cols)
__global__ __launch_bounds__(256) void repack_k(const float* __restrict__ s, float* __restrict__ d){
  int i = blockIdx.x * 256 + threadIdx.x;
  if (i < D_ * 512){
    int k = i >> 9, c = i & 511;
    int h = c >> 6, f = c & 63;
    d[i] = s[(size_t)(h * D_ + k) * GH_ + f];
  }
}

// ---------- GEMM: C[M,Nc] = act(A[M,K] @ W[K,Nc] + bias + resid), all fp32 ----------
__global__ __launch_bounds__(256) void gemm_k(
    const float* __restrict__ A, const float* __restrict__ W,
    const float* __restrict__ bias, const float* __restrict__ resid,
    float* __restrict__ C, int M, int Nc, int K, int act)
{
  __shared__ float As[64][20];
  __shared__ float Bs[16][68];
  int tid = threadIdx.x;
  int tx = tid & 15, ty = tid >> 4;
  int row0 = blockIdx.y << 6, col0 = blockIdx.x << 6;
  float acc[4][4] = {};
  int ra = tid >> 2, ca = (tid & 3) << 2;    // A tile 64x16
  int rb = tid >> 4, cb = (tid & 15) << 2;   // W tile 16x64

  for (int k0 = 0; k0 < K; k0 += 16){
    float4 av = *(const float4*)(A + (size_t)(row0 + ra) * K + k0 + ca);
    As[ra][ca+0]=av.x; As[ra][ca+1]=av.y; As[ra][ca+2]=av.z; As[ra][ca+3]=av.w;
    float4 wv = *(const float4*)(W + (size_t)(k0 + rb) * Nc + col0 + cb);
    Bs[rb][cb+0]=wv.x; Bs[rb][cb+1]=wv.y; Bs[rb][cb+2]=wv.z; Bs[rb][cb+3]=wv.w;
    __syncthreads();
    #pragma unroll
    for (int kk = 0; kk < 16; ++kk){
      float a[4], b[4];
      #pragma unroll
      for (int i = 0; i < 4; i++) a[i] = As[(ty<<2)+i][kk];
      #pragma unroll
      for (int j = 0; j < 4; j++) b[j] = Bs[kk][(tx<<2)+j];
      #pragma unroll
      for (int i = 0; i < 4; i++)
        #pragma unroll
        for (int j = 0; j < 4; j++)
          acc[i][j] = fmaf(a[i], b[j], acc[i][j]);
    }
    __syncthreads();
  }
  #pragma unroll
  for (int i = 0; i < 4; i++){
    int row = row0 + (ty<<2) + i;
    float4 rv;
    if (resid) rv = *(const float4*)(resid + (size_t)row * Nc + col0 + (tx<<2));
    float vals[4];
    #pragma unroll
    for (int j = 0; j < 4; j++){
      float c = acc[i][j];
      int col = col0 + (tx<<2) + j;
      if (bias)  c += bias[col];
      if (resid) c += (j==0?rv.x : j==1?rv.y : j==2?rv.z : rv.w);
      if (act == 1) c = c > 0.0f ? c : 0.2f * c;
      vals[j] = c;
    }
    *(float4*)(C + (size_t)row * Nc + col0 + (tx<<2)) = make_float4(vals[0],vals[1],vals[2],vals[3]);
  }
}

// ---------- GAT scores ----------
__global__ __launch_bounds__(256) void gat1_scores(const float* __restrict__ hall,
    const float* __restrict__ gata, float* __restrict__ s1, float* __restrict__ s2)
{
  int gw = blockIdx.x * 4 + (threadIdx.x >> 6);   // 0 .. H*B*N-1
  int lane = threadIdx.x & 63;
  int h = gw >> 13;          // / (B*N)
  int r = gw & 8191;         // b*N + n
  float v = hall[(size_t)r * D_ + h * 64 + lane];
  float p1 = v * gata[h * 128 + lane];
  float p2 = v * gata[h * 128 + 64 + lane];
  #pragma unroll
  for (int o = 32; o; o >>= 1){ p1 += __shfl_down(p1, o, 64); p2 += __shfl_down(p2, o, 64); }
  if (lane == 0){ s1[h * 8192 + r] = p1; s2[h * 8192 + r] = p2; }
}
__global__ __launch_bounds__(256) void gat2_scores(const float* __restrict__ h2,
    const float* __restrict__ gatoa, float* __restrict__ s1, float* __restrict__ s2)
{
  int r = blockIdx.x * 4 + (threadIdx.x >> 6);  // 0 .. B*N-1
  int lane = threadIdx.x & 63;
  float p1 = 0.0f, p2 = 0.0f;
  for (int c = lane; c < D_; c += 64){
    float v = h2[(size_t)r * D_ + c];
    p1 += v * gatoa[c];
    p2 += v * gatoa[D_ + c];
  }
  #pragma unroll
  for (int o = 32; o; o >>= 1){ p1 += __shfl_down(p1, o, 64); p2 += __shfl_down(p2, o, 64); }
  if (lane == 0){ s1[r] = p1; s2[r] = p2; }
}

// ---------- GAT layer 1 attention (per head, F=64, elu, write concat slot) ----------
__global__ __launch_bounds__(256) void gat_attn1(const int* __restrict__ adj,
    const float* __restrict__ s1, const float* __restrict__ s2,
    const float* __restrict__ hall, float* __restrict__ xc)
{
  __shared__ float sc[512];
  __shared__ float red[4];
  __shared__ float oacc[4][64];
  int tid = threadIdx.x;
  int idx = blockIdx.x;                 // (h*B + b)*N + i
  int i = idx & 511; idx >>= 9;
  int b = idx & 15;  int h = idx >> 4;
  int hb = h * 16 + b;
  float s1v = s1[hb * 512 + i];
  const int* arow = adj + ((size_t)b * N_ + i) * N_;
  float mx = -3.0e38f;
  for (int j = tid; j < N_; j += 256){
    float e = s1v + s2[hb * 512 + j];
    e = e > 0.0f ? e : 0.2f * e;
    if (arow[j] <= 0) e = -9.0e15f;
    sc[j] = e;
    mx = fmaxf(mx, e);
  }
  mx = block_max(mx, red);
  float sum = 0.0f;
  for (int j = tid; j < N_; j += 256){
    float p = expf(sc[j] - mx);
    sc[j] = p; sum += p;
  }
  sum = block_sum(sum, red);
  float inv = 1.0f / sum;
  int d = tid & 63, grp = tid >> 6;
  float acc = 0.0f;
  for (int j = grp; j < N_; j += 4)
    acc += sc[j] * hall[((size_t)(b * N_ + j)) * D_ + h * 64 + d];
  oacc[grp][d] = acc;
  __syncthreads();
  if (tid < 64){
    float r = (oacc[0][tid] + oacc[1][tid] + oacc[2][tid] + oacc[3][tid]) * inv;
    r = r > 0.0f ? r : expf(r) - 1.0f;   // elu (concat=True)
    xc[((size_t)(b * N_ + i)) * D_ + h * 64 + tid] = r;
  }
}

// ---------- GAT output layer (F=512): slot_graph_out = elu(hp) + x  (fp32 out) ----------
__global__ __launch_bounds__(256) void gat_attn2(const int* __restrict__ adj,
    const float* __restrict__ s1, const float* __restrict__ s2,
    const float* __restrict__ h2, const float* __restrict__ xf, float* __restrict__ out3)
{
  __shared__ float sc[512];
  __shared__ float red[4];
  int tid = threadIdx.x;
  int r = blockIdx.x;          // b*N + i
  int b = r >> 9;
  float s1v = s1[r];
  const int* arow = adj + (size_t)r * N_;
  float mx = -3.0e38f;
  for (int j = tid; j < N_; j += 256){
    float e = s1v + s2[b * 512 + j];
    e = e > 0.0f ? e : 0.2f * e;
    if (arow[j] <= 0) e = -9.0e15f;
    sc[j] = e;
    mx = fmaxf(mx, e);
  }
  mx = block_max(mx, red);
  float sum = 0.0f;
  for (int j = tid; j < N_; j += 256){
    float p = expf(sc[j] - mx);
    sc[j] = p; sum += p;
  }
  sum = block_sum(sum, red);
  float inv = 1.0f / sum;
  float acc0 = 0.0f, acc1 = 0.0f;
  for (int j = 0; j < N_; j++){
    float p = sc[j];
    const float* hrow = h2 + ((size_t)(b * N_ + j)) * D_;
    acc0 += p * hrow[tid];
    acc1 += p * hrow[tid + 256];
  }
  size_t ro = (size_t)r * D_;
  float hp0 = acc0 * inv, hp1 = acc1 * inv;
  hp0 = hp0 > 0.0f ? hp0 : expf(hp0) - 1.0f;
  hp1 = hp1 > 0.0f ? hp1 : expf(hp1) - 1.0f;
  out3[ro + tid]       = hp0 + xf[ro + tid];
  out3[ro + tid + 256] = hp1 + xf[ro + tid + 256];
}

// ---------- MHA fused masked-softmax attention: one block per (b,h,qi), fp32 ----------
__global__ __launch_bounds__(256) void mha_attn(const float* __restrict__ q, const float* __restrict__ k,
    const float* __restrict__ v, const int* __restrict__ mask, float* __restrict__ o, int Lq, int Lk)
{
  __shared__ float sc[512];
  __shared__ float qv[64];
  __shared__ float red[4];
  __shared__ float oacc[4][64];
  int tid = threadIdx.x;
  int bh = blockIdx.x;
  int qi = bh % Lq; bh /= Lq;
  int h = bh & 7; int b = bh >> 3;
  const float* qrow = q + ((size_t)(b * Lq + qi)) * D_ + h * 64;
  if (tid < 64) qv[tid] = qrow[tid];
  __syncthreads();
  float mx = -3.0e38f;
  for (int j = tid; j < Lk; j += 256){
    const float* krow = k + ((size_t)(b * Lk + j)) * D_ + h * 64;
    float dsum = 0.0f;
    #pragma unroll
    for (int c = 0; c < 64; c += 4){
      float4 k4 = *(const float4*)(krow + c);
      dsum += qv[c] * k4.x + qv[c+1] * k4.y + qv[c+2] * k4.z + qv[c+3] * k4.w;
    }
    dsum *= 0.125f;                                    // / sqrt(64)
    if (mask[((size_t)b * Lq + qi) * Lk + j] == 0) dsum = -1.0e9f;
    sc[j] = dsum;
    mx = fmaxf(mx, dsum);
  }
  mx = block_max(mx, red);
  float sum = 0.0f;
  for (int j = tid; j < Lk; j += 256){
    float p = expf(sc[j] - mx);
    sc[j] = p; sum += p;
  }
  sum = block_sum(sum, red);
  float inv = 1.0f / sum;
  int d = tid & 63, grp = tid >> 6;
  float acc = 0.0f;
  for (int j = grp; j < Lk; j += 4)
    acc += sc[j] * v[((size_t)(b * Lk + j)) * D_ + h * 64 + d];
  oacc[grp][d] = acc;
  __syncthreads();
  if (tid < 64)
    o[((size_t)(b * Lq + qi)) * D_ + h * 64 + tid] =
      (oacc[0][tid] + oacc[1][tid] + oacc[2][tid] + oacc[3][tid]) * inv;
}

// ---------- LayerNorm over D=512, one block per row, fp32 ----------
__global__ __launch_bounds__(256) void ln_k(const float* __restrict__ in,
    const float* __restrict__ g, const float* __restrict__ bta, float* __restrict__ out)
{
  __shared__ float red[4];
  int r = blockIdx.x, tid = threadIdx.x;
  const float* x = in + (size_t)r * D_;
  float v0 = x[tid], v1 = x[tid + 256];
  float mu = block_sum(v0 + v1, red) * (1.0f / 512.0f);
  float d0 = v0 - mu, d1 = v1 - mu;
  float var = block_sum(d0 * d0 + d1 * d1, red) * (1.0f / 512.0f);
  float inv = 1.0f / sqrtf(var + 1e-6f);
  out[(size_t)r * D_ + tid]       = d0 * inv * g[tid]       + bta[tid];
  out[(size_t)r * D_ + tid + 256] = d1 * inv * g[tid + 256] + bta[tid + 256];
}

// ---------- host-side MHA helper (all fp32) ----------
static void run_mha(hipStream_t st, const float* q_in, int Lq, const float* kv_in, int Lk,
                    const int* mask, const float* w, const float* g, const float* bt,
                    float* qb, float* kb, float* vb, float* ob, float* tmp, float* out)
{
  dim3 blk(256);
  gemm_k<<<dim3(D_/64,(B_*Lq)/64), blk, 0, st>>>(q_in,  w + 0*DD, nullptr, nullptr, qb, B_*Lq, D_, D_, 0);
  gemm_k<<<dim3(D_/64,(B_*Lk)/64), blk, 0, st>>>(kv_in, w + 1*DD, nullptr, nullptr, kb, B_*Lk, D_, D_, 0);
  gemm_k<<<dim3(D_/64,(B_*Lk)/64), blk, 0, st>>>(kv_in, w + 2*DD, nullptr, nullptr, vb, B_*Lk, D_, D_, 0);
  mha_attn<<<dim3(B_*NH_*Lq), blk, 0, st>>>(qb, kb, vb, mask, ob, Lq, Lk);
  gemm_k<<<dim3(D_/64,(B_*Lq)/64), blk, 0, st>>>(ob, w + 3*DD, nullptr, q_in, tmp, B_*Lq, D_, D_, 0);
  ln_k<<<dim3(B_*Lq), blk, 0, st>>>(tmp, g, bt, out);
}

extern "C" void kernel_launch(void* const* d_in, const int* in_sizes, int n_in,
                              void* d_out, int out_size, void* d_ws, size_t ws_size,
                              hipStream_t stream) {
  (void)in_sizes; (void)n_in; (void)out_size; (void)ws_size;

  const float* xf    = (const float*)d_in[0];
  const int* adj_i   = (const int*)d_in[2];
  const int* adj_s   = (const int*)d_in[3];
  const int* adj_is  = (const int*)d_in[4];
  const int* adj_si  = (const int*)d_in[5];
  const float* intent= (const float*)d_in[6];
  const float* gatW  = (const float*)d_in[7];
  const float* gata  = (const float*)d_in[8];
  const float* gatoW = (const float*)d_in[9];
  const float* gatoa = (const float*)d_in[10];
  const float* mhaw  = (const float*)d_in[11];
  const float* lng   = (const float*)d_in[12];
  const float* lnb   = (const float*)d_in[13];
  const float* linW1 = (const float*)d_in[14];
  const float* linb1 = (const float*)d_in[15];
  const float* linW2 = (const float*)d_in[16];
  const float* linb2 = (const float*)d_in[17];

  float* out0 = (float*)d_out;                   // slot_out      [B,N,D]   fp32
  float* out1 = out0 + BND;                      // slot_logits   [B,N,OUT] fp32
  float* out2 = out1 + (size_t)B_*N_*OUT_;       // slot_graph_out[B,N,D]   fp32

  // ---- workspace carve (all fp32, ~128.5 MB) ----
  float* Q    = (float*)d_ws;      // BND
  float* K    = Q   + BND;
  float* V    = K   + BND;
  float* O    = V   + BND;
  float* TMP  = O   + BND;
  float* HB1  = TMP + BND;
  float* HB2  = HB1 + BND;
  float* ha0  = HB2 + BND;         // BID each
  float* ha1  = ha0 + BID;
  float* ta   = ha1 + BID;
  float* tb   = ta  + BID;
  float* sqa  = tb  + BID;
  float* ska  = sqa + BID;
  float* sva  = ska + BID;
  float* soa  = sva + BID;
  float* stmp = soa + BID;
  float* Wcat = stmp+ BID;         // 262144
  float* s1   = Wcat+ 262144;      // 65536
  float* s2   = s1  + 65536;       // 65536
  float* s1o  = s2  + 65536;       // 8192
  float* s2o  = s1o + 8192;        // 8192

  dim3 blk(256);

  // ================= MHA stack =================
  bcast_k<<<BID/256, blk, 0, stream>>>(intent, ha0, BID);

  // ---- layer 0 (h_b = xf, h_a = ha0) ----
  run_mha(stream, ha0, NI_, ha0, NI_, adj_i,  mhaw +  0*DD, lng + 0*D_, lnb + 0*D_,
          sqa, ska, sva, soa, stmp, ta);                                   // a2a -> ta
  run_mha(stream, ha0, NI_, xf,  N_,  adj_si, mhaw + 12*DD, lng + 3*D_, lnb + 3*D_,
          sqa, K, V, soa, stmp, tb);                                       // b2a -> tb
  add_relu_k<<<BID/256, blk, 0, stream>>>(ta, tb, ha1, BID);               // h_a1
  run_mha(stream, xf, N_, xf, N_, adj_s,  mhaw +  4*DD, lng + 1*D_, lnb + 1*D_,
          Q, K, V, O, TMP, HB1);                                           // b2b -> HB1
  run_mha(stream, xf, N_, ha0, NI_, adj_is, mhaw + 8*DD, lng + 2*D_, lnb + 2*D_,
          Q, ska, sva, O, TMP, Q);                                         // a2b -> Q
  add_relu_ip_k<<<BND/256, blk, 0, stream>>>(HB1, Q, BND);                 // h_b1 = relu(b2b+a2b)

  // ---- layer 1 (h_b = HB1, h_a = ha1); a2a/b2a dead (final h_a unused) ----
  run_mha(stream, HB1, N_, HB1, N_, adj_s,  mhaw + 20*DD, lng + 5*D_, lnb + 5*D_,
          Q, K, V, O, TMP, HB2);                                           // b2b -> HB2
  run_mha(stream, HB1, N_, ha1, NI_, adj_is, mhaw + 24*DD, lng + 6*D_, lnb + 6*D_,
          Q, ska, sva, O, TMP, Q);                                         // a2b -> Q
  add_relu_ip_k<<<BND/256, blk, 0, stream>>>(HB2, Q, BND);                 // h_b2

  // ---- slot_out = x + h_b2 (fp32, straight into out0) ----
  add_k<<<BND/256, blk, 0, stream>>>(xf, HB2, out0, BND);
  // ---- logits = (leaky(slot_out@W1+b1))@W2+b2 ----
  gemm_k<<<dim3(D_/64, (B_*N_)/64), blk, 0, stream>>>(out0, linW1, linb1, nullptr, Q, B_*N_, D_, D_, 1);
  gemm_k<<<dim3(OUT_/64, (B_*N_)/64), blk, 0, stream>>>(Q, linW2, linb2, nullptr, out1, B_*N_, OUT_, D_, 0);

  // ================= GAT branch (reuses Q,K,V; writes out2) =================
  repack_k<<<(D_*512)/256, blk, 0, stream>>>(gatW, Wcat);
  gemm_k<<<dim3(D_/64, (B_*N_)/64), blk, 0, stream>>>(xf, Wcat, nullptr, nullptr, Q /*h_all*/, B_*N_, D_, D_, 0);
  gat1_scores<<<(H_*B_*N_)/4, blk, 0, stream>>>(Q, gata, s1, s2);
  gat_attn1<<<H_*B_*N_, blk, 0, stream>>>(adj_s, s1, s2, Q, K /*xc*/);
  gemm_k<<<dim3(D_/64, (B_*N_)/64), blk, 0, stream>>>(K, gatoW, nullptr, nullptr, V /*h2*/, B_*N_, D_, D_, 0);
  gat2_scores<<<(B_*N_)/4, blk, 0, stream>>>(V, gatoa, s1o, s2o);
  gat_attn2<<<B_*N_, blk, 0, stream>>>(adj_s, s1o, s2o, V, xf, out2);
}

// Round 7
// 2809.819 us; speedup vs baseline: 2.7705x; 2.7705x over previous
//
#include <hip/hip_runtime.h>

// B=16, N=512, D=512, NI=32, GH=64, H=8, L=2, OUT=128, heads=8
#define B_   16
#define N_   512
#define D_   512
#define NI_  32
#define GH_  64
#define H_   8
#define OUT_ 128
#define NH_  8

#define BND   (B_*N_*D_)     // 4194304
#define BID   (B_*NI_*D_)    // 262144
#define DD    (D_*D_)        // 262144

#define QT   16              // query tile for attention kernels
#define LSP  520             // padded score-row stride (520%32=8 -> distinct banks per q)

// blockDim must be 256
__device__ __forceinline__ float block_sum(float v, float* sm){
  #pragma unroll
  for (int o = 32; o; o >>= 1) v += __shfl_down(v, o, 64);
  int lane = threadIdx.x & 63, w = threadIdx.x >> 6;
  __syncthreads();
  if (lane == 0) sm[w] = v;
  __syncthreads();
  return sm[0] + sm[1] + sm[2] + sm[3];
}
__device__ __forceinline__ float block_max(float v, float* sm){
  #pragma unroll
  for (int o = 32; o; o >>= 1) v = fmaxf(v, __shfl_down(v, o, 64));
  int lane = threadIdx.x & 63, w = threadIdx.x >> 6;
  __syncthreads();
  if (lane == 0) sm[w] = v;
  __syncthreads();
  return fmaxf(fmaxf(sm[0], sm[1]), fmaxf(sm[2], sm[3]));
}

// ---------- elementwise (all fp32) ----------
__global__ __launch_bounds__(256) void bcast_k(const float* __restrict__ s, float* __restrict__ d, int n){
  int i = blockIdx.x * 256 + threadIdx.x;
  if (i < n) d[i] = s[i & (NI_*D_ - 1)];
}
__global__ __launch_bounds__(256) void add_relu_k(const float* __restrict__ a, const float* __restrict__ b,
                                                  float* __restrict__ o, int n){
  int i = blockIdx.x * 256 + threadIdx.x;
  if (i < n){ float v = a[i] + b[i]; o[i] = v > 0.0f ? v : 0.0f; }
}
__global__ __launch_bounds__(256) void add_relu_ip_k(float* __restrict__ a, const float* __restrict__ b, int n){
  int i = blockIdx.x * 256 + threadIdx.x;
  if (i < n){ float v = a[i] + b[i]; a[i] = v > 0.0f ? v : 0.0f; }
}
__global__ __launch_bounds__(256) void add_k(const float* __restrict__ a, const float* __restrict__ b,
                                             float* __restrict__ o, int n){
  int i = blockIdx.x * 256 + threadIdx.x;
  if (i < n) o[i] = a[i] + b[i];
}
// gat_W [H,D,GH] -> Wcat [D, H*GH] (head-major concat cols)
__global__ __launch_bounds__(256) void repack_k(const float* __restrict__ s, float* __restrict__ d){
  int i = blockIdx.x * 256 + threadIdx.x;
  if (i < D_ * 512){
    int k = i >> 9, c = i & 511;
    int h = c >> 6, f = c & 63;
    d[i] = s[(size_t)(h * D_ + k) * GH_ + f];
  }
}

// ---------- GEMM (batched): C = act(A @ W + bias) + resid ----------
// act: 0=none, 1=leaky(0.2) (pre-resid), 2=elu (pre-resid). Batch via blockIdx.z with strides.
__global__ __launch_bounds__(256) void gemm_k(
    const float* __restrict__ A, const float* __restrict__ W,
    const float* __restrict__ bias, const float* __restrict__ resid,
    float* __restrict__ C, int M, int Nc, int K, int act,
    size_t sA, size_t sW, size_t sC, size_t sR)
{
  __shared__ float As[16][68];   // [k][row]  (transposed for b128 fragment reads)
  __shared__ float Bs[16][68];   // [k][col]
  const float* Ab = A + (size_t)blockIdx.z * sA;
  const float* Wb = W + (size_t)blockIdx.z * sW;
  const float* Rb = resid ? resid + (size_t)blockIdx.z * sR : nullptr;
  float*       Cb = C + (size_t)blockIdx.z * sC;

  int tid = threadIdx.x;
  int tx = tid & 15, ty = tid >> 4;
  int row0 = blockIdx.y << 6, col0 = blockIdx.x << 6;
  float acc[4][4] = {};
  int ra = tid >> 2, ca = (tid & 3) << 2;    // A tile 64x16
  int rb = tid >> 4, cb = (tid & 15) << 2;   // W tile 16x64

  for (int k0 = 0; k0 < K; k0 += 16){
    float4 av = *(const float4*)(Ab + (size_t)(row0 + ra) * K + k0 + ca);
    As[ca+0][ra]=av.x; As[ca+1][ra]=av.y; As[ca+2][ra]=av.z; As[ca+3][ra]=av.w;
    float4 wv = *(const float4*)(Wb + (size_t)(k0 + rb) * Nc + col0 + cb);
    Bs[rb][cb+0]=wv.x; Bs[rb][cb+1]=wv.y; Bs[rb][cb+2]=wv.z; Bs[rb][cb+3]=wv.w;
    __syncthreads();
    #pragma unroll
    for (int kk = 0; kk < 16; ++kk){
      float a[4], b[4];
      #pragma unroll
      for (int i = 0; i < 4; i++) a[i] = As[kk][(ty<<2)+i];
      #pragma unroll
      for (int j = 0; j < 4; j++) b[j] = Bs[kk][(tx<<2)+j];
      #pragma unroll
      for (int i = 0; i < 4; i++)
        #pragma unroll
        for (int j = 0; j < 4; j++)
          acc[i][j] = fmaf(a[i], b[j], acc[i][j]);
    }
    __syncthreads();
  }
  #pragma unroll
  for (int i = 0; i < 4; i++){
    int row = row0 + (ty<<2) + i;
    float4 rv;
    if (Rb) rv = *(const float4*)(Rb + (size_t)row * Nc + col0 + (tx<<2));
    float vals[4];
    #pragma unroll
    for (int j = 0; j < 4; j++){
      float c = acc[i][j];
      int col = col0 + (tx<<2) + j;
      if (bias)  c += bias[col];
      if (act == 1) c = c > 0.0f ? c : 0.2f * c;
      else if (act == 2) c = c > 0.0f ? c : expf(c) - 1.0f;
      if (Rb) c += (j==0?rv.x : j==1?rv.y : j==2?rv.z : rv.w);
      vals[j] = c;
    }
    *(float4*)(Cb + (size_t)row * Nc + col0 + (tx<<2)) = make_float4(vals[0],vals[1],vals[2],vals[3]);
  }
}

// ---------- tiled MHA attention: block per (qtile, h, b); D=64/head ----------
// q:[B,Lq,512] k,v:[B,Lk,512] mask:[B,Lq,Lk] o:[B,Lq,512]. Lq,Lk multiples of 16.
__global__ __launch_bounds__(256) void attn_tiled(
    const float* __restrict__ q, const float* __restrict__ k, const float* __restrict__ v,
    const int* __restrict__ mask, float* __restrict__ o, int Lq, int Lk)
{
  __shared__ float Qs[64][QT];      // [d][q]
  __shared__ float KVs[128*64];     // K tile as [d][j](stride 128) then V tile as [j][d](stride 64)
  __shared__ float Ls[QT][LSP];     // scores / probabilities
  __shared__ float invs[QT];
  int tid = threadIdx.x;
  int q0 = blockIdx.x * QT, h = blockIdx.y, b = blockIdx.z;

  // load Q tile transposed
  {
    int qr = tid >> 4, d4 = (tid & 15) << 2;
    float4 qq = *(const float4*)(q + ((size_t)(b*Lq + q0 + qr))*512 + h*64 + d4);
    Qs[d4+0][qr]=qq.x; Qs[d4+1][qr]=qq.y; Qs[d4+2][qr]=qq.z; Qs[d4+3][qr]=qq.w;
  }
  __syncthreads();

  // ---- pass 1: scores ----
  for (int jt = 0; jt < Lk; jt += 128){
    int JT = min(128, Lk - jt);
    for (int x = tid; x < JT*16; x += 256){
      int jr = x >> 4, d4 = (x & 15) << 2;
      float4 kk = *(const float4*)(k + ((size_t)(b*Lk + jt + jr))*512 + h*64 + d4);
      KVs[(d4+0)*128 + jr]=kk.x; KVs[(d4+1)*128 + jr]=kk.y;
      KVs[(d4+2)*128 + jr]=kk.z; KVs[(d4+3)*128 + jr]=kk.w;
    }
    __syncthreads();
    int qi = (tid >> 5) << 1;       // 0,2,..,14
    int ji = (tid & 31) << 2;       // 0..124
    if (ji < JT){
      float a00=0,a01=0,a02=0,a03=0,a10=0,a11=0,a12=0,a13=0;
      #pragma unroll
      for (int d = 0; d < 64; d++){
        float x0 = Qs[d][qi], x1 = Qs[d][qi+1];
        const float4 kv = *(const float4*)&KVs[d*128 + ji];
        a00 = fmaf(x0, kv.x, a00); a01 = fmaf(x0, kv.y, a01);
        a02 = fmaf(x0, kv.z, a02); a03 = fmaf(x0, kv.w, a03);
        a10 = fmaf(x1, kv.x, a10); a11 = fmaf(x1, kv.y, a11);
        a12 = fmaf(x1, kv.z, a12); a13 = fmaf(x1, kv.w, a13);
      }
      const int4 m0 = *(const int4*)(mask + ((size_t)b*Lq + q0+qi  )*Lk + jt + ji);
      const int4 m1 = *(const int4*)(mask + ((size_t)b*Lq + q0+qi+1)*Lk + jt + ji);
      float4 e0, e1;
      e0.x = m0.x ? a00*0.125f : -1.0e9f;  e0.y = m0.y ? a01*0.125f : -1.0e9f;
      e0.z = m0.z ? a02*0.125f : -1.0e9f;  e0.w = m0.w ? a03*0.125f : -1.0e9f;
      e1.x = m1.x ? a10*0.125f : -1.0e9f;  e1.y = m1.y ? a11*0.125f : -1.0e9f;
      e1.z = m1.z ? a12*0.125f : -1.0e9f;  e1.w = m1.w ? a13*0.125f : -1.0e9f;
      *(float4*)&Ls[qi  ][jt+ji] = e0;
      *(float4*)&Ls[qi+1][jt+ji] = e1;
    }
    __syncthreads();
  }

  // ---- pass 2: softmax over Lk per q-row (16 lanes per row) ----
  {
    int qq = tid >> 4, part = tid & 15;
    float mx = -3.0e38f;
    for (int j = part; j < Lk; j += 16) mx = fmaxf(mx, Ls[qq][j]);
    #pragma unroll
    for (int m = 1; m < 16; m <<= 1) mx = fmaxf(mx, __shfl_xor(mx, m, 16));
    float sum = 0.0f;
    for (int j = part; j < Lk; j += 16){
      float p = expf(Ls[qq][j] - mx);
      Ls[qq][j] = p; sum += p;
    }
    #pragma unroll
    for (int m = 1; m < 16; m <<= 1) sum += __shfl_xor(sum, m, 16);
    if (part == 0) invs[qq] = 1.0f / sum;
  }
  __syncthreads();

  // ---- pass 3: P @ V ----
  int qq = tid >> 4, d4 = (tid & 15) << 2;
  float ax=0, ay=0, az=0, aw=0;
  for (int jt = 0; jt < Lk; jt += 128){
    int JT = min(128, Lk - jt);
    for (int x = tid; x < JT*16; x += 256){
      int jr = x >> 4, dd = (x & 15) << 2;
      *(float4*)&KVs[jr*64 + dd] =
        *(const float4*)(v + ((size_t)(b*Lk + jt + jr))*512 + h*64 + dd);
    }
    __syncthreads();
    #pragma unroll 4
    for (int jj = 0; jj < JT; jj++){
      float p = Ls[qq][jt + jj];
      const float4 vv = *(const float4*)&KVs[jj*64 + d4];
      ax = fmaf(p, vv.x, ax); ay = fmaf(p, vv.y, ay);
      az = fmaf(p, vv.z, az); aw = fmaf(p, vv.w, aw);
    }
    __syncthreads();
  }
  float inv = invs[qq];
  *(float4*)(o + ((size_t)(b*Lq + q0 + qq))*512 + h*64 + d4) =
    make_float4(ax*inv, ay*inv, az*inv, aw*inv);
}

// ---------- GAT scores (unchanged) ----------
__global__ __launch_bounds__(256) void gat1_scores(const float* __restrict__ hall,
    const float* __restrict__ gata, float* __restrict__ s1, float* __restrict__ s2)
{
  int gw = blockIdx.x * 4 + (threadIdx.x >> 6);
  int lane = threadIdx.x & 63;
  int h = gw >> 13;
  int r = gw & 8191;
  float v = hall[(size_t)r * D_ + h * 64 + lane];
  float p1 = v * gata[h * 128 + lane];
  float p2 = v * gata[h * 128 + 64 + lane];
  #pragma unroll
  for (int o = 32; o; o >>= 1){ p1 += __shfl_down(p1, o, 64); p2 += __shfl_down(p2, o, 64); }
  if (lane == 0){ s1[h * 8192 + r] = p1; s2[h * 8192 + r] = p2; }
}
__global__ __launch_bounds__(256) void gat2_scores(const float* __restrict__ h2,
    const float* __restrict__ gatoa, float* __restrict__ s1, float* __restrict__ s2)
{
  int r = blockIdx.x * 4 + (threadIdx.x >> 6);
  int lane = threadIdx.x & 63;
  float p1 = 0.0f, p2 = 0.0f;
  for (int c = lane; c < D_; c += 64){
    float v = h2[(size_t)r * D_ + c];
    p1 += v * gatoa[c];
    p2 += v * gatoa[D_ + c];
  }
  #pragma unroll
  for (int o = 32; o; o >>= 1){ p1 += __shfl_down(p1, o, 64); p2 += __shfl_down(p2, o, 64); }
  if (lane == 0){ s1[r] = p1; s2[r] = p2; }
}

// ---------- tiled GAT layer-1 attention: block per (qtile, h, b) ----------
// scores rank-1: leaky(s1[i]+s2[j]), mask adj -> -9e15; PV over hall head slice; elu output.
__global__ __launch_bounds__(256) void gat1_attn_tiled(const int* __restrict__ adj,
    const float* __restrict__ s1, const float* __restrict__ s2,
    const float* __restrict__ hall, float* __restrict__ xc)
{
  __shared__ float KVs[128*64];
  __shared__ float Ls[QT][LSP];
  __shared__ float invs[QT];
  int tid = threadIdx.x;
  int q0 = blockIdx.x * QT, h = blockIdx.y, b = blockIdx.z;
  int hb = h * 8192 + b * 512;

  // ---- scores ----
  {
    int qi = (tid >> 5) << 1;
    int ji = (tid & 31) << 2;
    float s10 = s1[hb + q0 + qi], s11 = s1[hb + q0 + qi + 1];
    for (int jt = 0; jt < 512; jt += 128){
      const float4 s2v = *(const float4*)(s2 + hb + jt + ji);
      const int4 m0 = *(const int4*)(adj + ((size_t)(b*512) + q0+qi  )*512 + jt + ji);
      const int4 m1 = *(const int4*)(adj + ((size_t)(b*512) + q0+qi+1)*512 + jt + ji);
      float4 e0, e1;
      float t;
      t = s10 + s2v.x; t = t>0?t:0.2f*t; e0.x = m0.x>0 ? t : -9.0e15f;
      t = s10 + s2v.y; t = t>0?t:0.2f*t; e0.y = m0.y>0 ? t : -9.0e15f;
      t = s10 + s2v.z; t = t>0?t:0.2f*t; e0.z = m0.z>0 ? t : -9.0e15f;
      t = s10 + s2v.w; t = t>0?t:0.2f*t; e0.w = m0.w>0 ? t : -9.0e15f;
      t = s11 + s2v.x; t = t>0?t:0.2f*t; e1.x = m1.x>0 ? t : -9.0e15f;
      t = s11 + s2v.y; t = t>0?t:0.2f*t; e1.y = m1.y>0 ? t : -9.0e15f;
      t = s11 + s2v.z; t = t>0?t:0.2f*t; e1.z = m1.z>0 ? t : -9.0e15f;
      t = s11 + s2v.w; t = t>0?t:0.2f*t; e1.w = m1.w>0 ? t : -9.0e15f;
      *(float4*)&Ls[qi  ][jt+ji] = e0;
      *(float4*)&Ls[qi+1][jt+ji] = e1;
    }
  }
  __syncthreads();

  // ---- softmax ----
  {
    int qq = tid >> 4, part = tid & 15;
    float mx = -3.0e38f;
    for (int j = part; j < 512; j += 16) mx = fmaxf(mx, Ls[qq][j]);
    #pragma unroll
    for (int m = 1; m < 16; m <<= 1) mx = fmaxf(mx, __shfl_xor(mx, m, 16));
    float sum = 0.0f;
    for (int j = part; j < 512; j += 16){
      float p = expf(Ls[qq][j] - mx);
      Ls[qq][j] = p; sum += p;
    }
    #pragma unroll
    for (int m = 1; m < 16; m <<= 1) sum += __shfl_xor(sum, m, 16);
    if (part == 0) invs[qq] = 1.0f / sum;
  }
  __syncthreads();

  // ---- P @ hall(head slice), elu, write concat slot ----
  int qq = tid >> 4, d4 = (tid & 15) << 2;
  float ax=0, ay=0, az=0, aw=0;
  for (int jt = 0; jt < 512; jt += 128){
    for (int x = tid; x < 128*16; x += 256){
      int jr = x >> 4, dd = (x & 15) << 2;
      *(float4*)&KVs[jr*64 + dd] =
        *(const float4*)(hall + ((size_t)(b*512 + jt + jr))*512 + h*64 + dd);
    }
    __syncthreads();
    #pragma unroll 4
    for (int jj = 0; jj < 128; jj++){
      float p = Ls[qq][jt + jj];
      const float4 vv = *(const float4*)&KVs[jj*64 + d4];
      ax = fmaf(p, vv.x, ax); ay = fmaf(p, vv.y, ay);
      az = fmaf(p, vv.z, az); aw = fmaf(p, vv.w, aw);
    }
    __syncthreads();
  }
  float inv = invs[qq];
  ax*=inv; ay*=inv; az*=inv; aw*=inv;
  ax = ax>0?ax:expf(ax)-1.0f;  ay = ay>0?ay:expf(ay)-1.0f;
  az = az>0?az:expf(az)-1.0f;  aw = aw>0?aw:expf(aw)-1.0f;
  *(float4*)(xc + ((size_t)(b*512 + q0 + qq))*512 + h*64 + d4) = make_float4(ax,ay,az,aw);
}

// ---------- GAT output-layer probabilities: one block per row; P normalized ----------
__global__ __launch_bounds__(256) void gat2_prob(const int* __restrict__ adj,
    const float* __restrict__ s1, const float* __restrict__ s2, float* __restrict__ P)
{
  __shared__ float red[4];
  int r = blockIdx.x, tid = threadIdx.x;
  int b = r >> 9;
  float s1v = s1[r];
  float e0, e1;
  {
    float t = s1v + s2[b*512 + tid];       t = t>0?t:0.2f*t;
    e0 = adj[(size_t)r*512 + tid]       > 0 ? t : -9.0e15f;
    t = s1v + s2[b*512 + tid + 256];       t = t>0?t:0.2f*t;
    e1 = adj[(size_t)r*512 + tid + 256] > 0 ? t : -9.0e15f;
  }
  float mx = block_max(fmaxf(e0, e1), red);
  float p0 = expf(e0 - mx), p1 = expf(e1 - mx);
  float s = block_sum(p0 + p1, red);
  float inv = 1.0f / s;
  P[(size_t)r*512 + tid]       = p0 * inv;
  P[(size_t)r*512 + tid + 256] = p1 * inv;
}

// ---------- LayerNorm over D=512, one block per row ----------
__global__ __launch_bounds__(256) void ln_k(const float* __restrict__ in,
    const float* __restrict__ g, const float* __restrict__ bta, float* __restrict__ out)
{
  __shared__ float red[4];
  int r = blockIdx.x, tid = threadIdx.x;
  const float* x = in + (size_t)r * D_;
  float v0 = x[tid], v1 = x[tid + 256];
  float mu = block_sum(v0 + v1, red) * (1.0f / 512.0f);
  float d0 = v0 - mu, d1 = v1 - mu;
  float var = block_sum(d0 * d0 + d1 * d1, red) * (1.0f / 512.0f);
  float inv = 1.0f / sqrtf(var + 1e-6f);
  out[(size_t)r * D_ + tid]       = d0 * inv * g[tid]       + bta[tid];
  out[(size_t)r * D_ + tid + 256] = d1 * inv * g[tid + 256] + bta[tid + 256];
}

// ---------- host-side MHA helper ----------
static void run_mha(hipStream_t st, const float* q_in, int Lq, const float* kv_in, int Lk,
                    const int* mask, const float* w, const float* g, const float* bt,
                    float* qb, float* kb, float* vb, float* ob, float* tmp, float* out)
{
  dim3 blk(256);
  gemm_k<<<dim3(D_/64,(B_*Lq)/64,1), blk, 0, st>>>(q_in,  w + 0*DD, nullptr, nullptr, qb, B_*Lq, D_, D_, 0, 0,0,0,0);
  gemm_k<<<dim3(D_/64,(B_*Lk)/64,1), blk, 0, st>>>(kv_in, w + 1*DD, nullptr, nullptr, kb, B_*Lk, D_, D_, 0, 0,0,0,0);
  gemm_k<<<dim3(D_/64,(B_*Lk)/64,1), blk, 0, st>>>(kv_in, w + 2*DD, nullptr, nullptr, vb, B_*Lk, D_, D_, 0, 0,0,0,0);
  attn_tiled<<<dim3(Lq/QT, NH_, B_), blk, 0, st>>>(qb, kb, vb, mask, ob, Lq, Lk);
  gemm_k<<<dim3(D_/64,(B_*Lq)/64,1), blk, 0, st>>>(ob, w + 3*DD, nullptr, q_in, tmp, B_*Lq, D_, D_, 0, 0,0,0,0);
  ln_k<<<dim3(B_*Lq), blk, 0, st>>>(tmp, g, bt, out);
}

extern "C" void kernel_launch(void* const* d_in, const int* in_sizes, int n_in,
                              void* d_out, int out_size, void* d_ws, size_t ws_size,
                              hipStream_t stream) {
  (void)in_sizes; (void)n_in; (void)out_size; (void)ws_size;

  const float* xf    = (const float*)d_in[0];
  const int* adj_i   = (const int*)d_in[2];
  const int* adj_s   = (const int*)d_in[3];
  const int* adj_is  = (const int*)d_in[4];
  const int* adj_si  = (const int*)d_in[5];
  const float* intent= (const float*)d_in[6];
  const float* gatW  = (const float*)d_in[7];
  const float* gata  = (const float*)d_in[8];
  const float* gatoW = (const float*)d_in[9];
  const float* gatoa = (const float*)d_in[10];
  const float* mhaw  = (const float*)d_in[11];
  const float* lng   = (const float*)d_in[12];
  const float* lnb   = (const float*)d_in[13];
  const float* linW1 = (const float*)d_in[14];
  const float* linb1 = (const float*)d_in[15];
  const float* linW2 = (const float*)d_in[16];
  const float* linb2 = (const float*)d_in[17];

  float* out0 = (float*)d_out;                   // slot_out      [B,N,D]
  float* out1 = out0 + BND;                      // slot_logits   [B,N,OUT]
  float* out2 = out1 + (size_t)B_*N_*OUT_;       // slot_graph_out[B,N,D]

  // ---- workspace carve (all fp32, ~128.5 MB) ----
  float* Q    = (float*)d_ws;      // BND
  float* K    = Q   + BND;
  float* V    = K   + BND;
  float* O    = V   + BND;
  float* TMP  = O   + BND;
  float* HB1  = TMP + BND;
  float* HB2  = HB1 + BND;
  float* ha0  = HB2 + BND;         // BID each
  float* ha1  = ha0 + BID;
  float* ta   = ha1 + BID;
  float* tb   = ta  + BID;
  float* sqa  = tb  + BID;
  float* ska  = sqa + BID;
  float* sva  = ska + BID;
  float* soa  = sva + BID;
  float* stmp = soa + BID;
  float* Wcat = stmp+ BID;         // 262144
  float* s1   = Wcat+ 262144;      // 65536
  float* s2   = s1  + 65536;       // 65536
  float* s1o  = s2  + 65536;       // 8192
  float* s2o  = s1o + 8192;        // 8192

  dim3 blk(256);

  // ================= MHA stack =================
  bcast_k<<<BID/256, blk, 0, stream>>>(intent, ha0, BID);

  // ---- layer 0 (h_b = xf, h_a = ha0) ----
  run_mha(stream, ha0, NI_, ha0, NI_, adj_i,  mhaw +  0*DD, lng + 0*D_, lnb + 0*D_,
          sqa, ska, sva, soa, stmp, ta);                                   // a2a -> ta
  run_mha(stream, ha0, NI_, xf,  N_,  adj_si, mhaw + 12*DD, lng + 3*D_, lnb + 3*D_,
          sqa, K, V, soa, stmp, tb);                                       // b2a -> tb
  add_relu_k<<<BID/256, blk, 0, stream>>>(ta, tb, ha1, BID);               // h_a1
  run_mha(stream, xf, N_, xf, N_, adj_s,  mhaw +  4*DD, lng + 1*D_, lnb + 1*D_,
          Q, K, V, O, TMP, HB1);                                           // b2b -> HB1
  run_mha(stream, xf, N_, ha0, NI_, adj_is, mhaw + 8*DD, lng + 2*D_, lnb + 2*D_,
          Q, ska, sva, O, TMP, Q);                                         // a2b -> Q
  add_relu_ip_k<<<BND/256, blk, 0, stream>>>(HB1, Q, BND);                 // h_b1

  // ---- layer 1 (h_b = HB1, h_a = ha1); a2a/b2a dead ----
  run_mha(stream, HB1, N_, HB1, N_, adj_s,  mhaw + 20*DD, lng + 5*D_, lnb + 5*D_,
          Q, K, V, O, TMP, HB2);                                           // b2b -> HB2
  run_mha(stream, HB1, N_, ha1, NI_, adj_is, mhaw + 24*DD, lng + 6*D_, lnb + 6*D_,
          Q, ska, sva, O, TMP, Q);                                         // a2b -> Q
  add_relu_ip_k<<<BND/256, blk, 0, stream>>>(HB2, Q, BND);                 // h_b2

  // ---- slot_out = x + h_b2 ----
  add_k<<<BND/256, blk, 0, stream>>>(xf, HB2, out0, BND);
  // ---- logits ----
  gemm_k<<<dim3(D_/64, (B_*N_)/64, 1), blk, 0, stream>>>(out0, linW1, linb1, nullptr, Q, B_*N_, D_, D_, 1, 0,0,0,0);
  gemm_k<<<dim3(OUT_/64, (B_*N_)/64, 1), blk, 0, stream>>>(Q, linW2, linb2, nullptr, out1, B_*N_, OUT_, D_, 0, 0,0,0,0);

  // ================= GAT branch =================
  repack_k<<<(D_*512)/256, blk, 0, stream>>>(gatW, Wcat);
  gemm_k<<<dim3(D_/64, (B_*N_)/64, 1), blk, 0, stream>>>(xf, Wcat, nullptr, nullptr, Q /*h_all*/, B_*N_, D_, D_, 0, 0,0,0,0);
  gat1_scores<<<(H_*B_*N_)/4, blk, 0, stream>>>(Q, gata, s1, s2);
  gat1_attn_tiled<<<dim3(N_/QT, H_, B_), blk, 0, stream>>>(adj_s, s1, s2, Q, K /*xc*/);
  gemm_k<<<dim3(D_/64, (B_*N_)/64, 1), blk, 0, stream>>>(K, gatoW, nullptr, nullptr, V /*h2*/, B_*N_, D_, D_, 0, 0,0,0,0);
  gat2_scores<<<(B_*N_)/4, blk, 0, stream>>>(V, gatoa, s1o, s2o);
  gat2_prob<<<B_*N_, blk, 0, stream>>>(adj_s, s1o, s2o, O /*P*/);
  // out2 = elu(P @ h2) + x   (batched over B)
  gemm_k<<<dim3(D_/64, N_/64, B_), blk, 0, stream>>>(O, V, nullptr, xf, out2, N_, D_, D_, 2,
                                                     (size_t)N_*N_, (size_t)N_*D_, (size_t)N_*D_, (size_t)N_*D_);
}

// Round 8
// 2124.754 us; speedup vs baseline: 3.6638x; 1.3224x over previous
//
#include <hip/hip_runtime.h>

// B=16, N=512, D=512, NI=32, GH=64, H=8, L=2, OUT=128, heads=8
#define B_   16
#define N_   512
#define D_   512
#define NI_  32
#define GH_  64
#define H_   8
#define OUT_ 128
#define NH_  8

#define BND   (B_*N_*D_)     // 4194304
#define BID   (B_*NI_*D_)    // 262144
#define DD    (D_*D_)        // 262144

#define QT   16
#define LSP  520

typedef unsigned short u16;
typedef unsigned int   u32;
typedef __attribute__((ext_vector_type(8))) short short8;
typedef __attribute__((ext_vector_type(4))) float f32x4;

__device__ __forceinline__ u16 f2bf(float f){
  u32 x = __float_as_uint(f);
  x += 0x7fffu + ((x >> 16) & 1u);   // RNE
  return (u16)(x >> 16);
}

// blockDim must be 256
__device__ __forceinline__ float block_sum(float v, float* sm){
  #pragma unroll
  for (int o = 32; o; o >>= 1) v += __shfl_down(v, o, 64);
  int lane = threadIdx.x & 63, w = threadIdx.x >> 6;
  __syncthreads();
  if (lane == 0) sm[w] = v;
  __syncthreads();
  return sm[0] + sm[1] + sm[2] + sm[3];
}
__device__ __forceinline__ float block_max(float v, float* sm){
  #pragma unroll
  for (int o = 32; o; o >>= 1) v = fmaxf(v, __shfl_down(v, o, 64));
  int lane = threadIdx.x & 63, w = threadIdx.x >> 6;
  __syncthreads();
  if (lane == 0) sm[w] = v;
  __syncthreads();
  return fmaxf(fmaxf(sm[0], sm[1]), fmaxf(sm[2], sm[3]));
}

// ---------- elementwise ----------
__global__ __launch_bounds__(256) void bcast_k(const float* __restrict__ s, float* __restrict__ d, int n){
  int i = blockIdx.x * 256 + threadIdx.x;
  if (i < n) d[i] = s[i & (NI_*D_ - 1)];
}
__global__ __launch_bounds__(256) void add_relu_k(const float* __restrict__ a, const float* __restrict__ b,
                                                  float* __restrict__ o, int n){
  int i = blockIdx.x * 256 + threadIdx.x;
  if (i < n){ float v = a[i] + b[i]; o[i] = v > 0.0f ? v : 0.0f; }
}
__global__ __launch_bounds__(256) void add_relu_ip_k(float* __restrict__ a, const float* __restrict__ b, int n){
  int i = blockIdx.x * 256 + threadIdx.x;
  if (i < n){ float v = a[i] + b[i]; a[i] = v > 0.0f ? v : 0.0f; }
}
__global__ __launch_bounds__(256) void add_k(const float* __restrict__ a, const float* __restrict__ b,
                                             float* __restrict__ o, int n){
  int i = blockIdx.x * 256 + threadIdx.x;
  if (i < n) o[i] = a[i] + b[i];
}

// ---------- weight swizzle into MFMA B-fragment order ----------
// Bsw unit (s, nt, lane): holds W[k = s*32 + (lane>>4)*8 + j][n = nt*16 + (lane&15)], j=0..7
// offset = ((s*(Nc/16) + nt)*64 + lane)*8 + j
__global__ __launch_bounds__(256) void swz_k(const float* __restrict__ W, u16* __restrict__ o,
                                             int Nc, size_t sW, size_t sO){
  int gw = blockIdx.x * 4 + (threadIdx.x >> 6);
  int lane = threadIdx.x & 63;
  int ntc = Nc >> 4;
  int s = gw / ntc, nt = gw - s * ntc;
  const float* Wb = W + sW * blockIdx.y;
  u16* ob = o + sO * blockIdx.y;
  int n = nt*16 + (lane & 15);
  int kb = s*32 + ((lane >> 4) << 3);
  u16 t8[8];
  #pragma unroll
  for (int j = 0; j < 8; j++) t8[j] = f2bf(Wb[(size_t)(kb + j) * Nc + n]);
  *(short8*)&ob[((size_t)(s * ntc + nt) * 64 + lane) * 8] = *(short8*)t8;
}
// gat_W [H,D,GH] -> head-major-concat [D,512], swizzled
__global__ __launch_bounds__(256) void swz_gatW_k(const float* __restrict__ gw_, u16* __restrict__ o){
  int gw = blockIdx.x * 4 + (threadIdx.x >> 6);  // 512 waves
  int lane = threadIdx.x & 63;
  int s = gw >> 5, nt = gw & 31;
  int n = nt*16 + (lane & 15);
  int h = n >> 6, f = n & 63;
  int kb = s*32 + ((lane >> 4) << 3);
  u16 t8[8];
  #pragma unroll
  for (int j = 0; j < 8; j++) t8[j] = f2bf(gw_[((size_t)(h*512) + kb + j) * 64 + f]);
  *(short8*)&o[((size_t)(s*32 + nt) * 64 + lane) * 8] = *(short8*)t8;
}

// ---------- MFMA GEMM: C[M,Nc](f32) = act(A[M,512](f32->bf16) @ Bsw + bias) + resid ----------
// 128x128 tile, 4 waves, each wave 64x64 (4x4 of 16x16). K = 512 fixed. act: 0 none, 1 leaky.
__global__ __launch_bounds__(256) void gemm_mfma(
    const float* __restrict__ A, const u16* __restrict__ Bw,
    const float* __restrict__ bias, const float* __restrict__ resid,
    float* __restrict__ C, int Nc, int act)
{
  __shared__ u16 As[128*64];   // frag order: ((mt*2+kt)*64 + lane)*8 + j
  __shared__ u16 Bs[64*128];   // frag order: ((kt*8 + nt)*64 + lane)*8 + j
  int tid = threadIdx.x, lane = tid & 63, wave = tid >> 6;
  int wm = wave & 1, wn = wave >> 1;
  int row0 = blockIdx.y << 7, col0 = blockIdx.x << 7;
  int ntc = Nc >> 4, nt0 = col0 >> 4;

  f32x4 acc[4][4] = {};

  for (int ks = 0; ks < 8; ks++){
    // stage A (fp32 -> bf16, fragment order)
    #pragma unroll
    for (int r = 0; r < 4; r++){
      int u = tid + (r << 8);
      int l = u & 63, kt = (u >> 6) & 1, mt = u >> 7;
      const float* src = A + (size_t)(row0 + (mt << 4) + (l & 15)) * 512
                           + (ks << 6) + (kt << 5) + ((l >> 4) << 3);
      float4 f0 = *(const float4*)src, f1 = *(const float4*)(src + 4);
      u16 t8[8] = {f2bf(f0.x), f2bf(f0.y), f2bf(f0.z), f2bf(f0.w),
                   f2bf(f1.x), f2bf(f1.y), f2bf(f1.z), f2bf(f1.w)};
      *(short8*)&As[(size_t)u * 8] = *(short8*)t8;
    }
    // stage B (straight contiguous copy of pre-swizzled chunk)
    #pragma unroll
    for (int kt = 0; kt < 2; kt++){
      const u16* sb = Bw + ((size_t)((ks*2 + kt) * ntc + nt0) << 9);
      #pragma unroll
      for (int r = 0; r < 2; r++){
        int uu = tid + (r << 8);
        *(short8*)&Bs[(kt << 12) + ((size_t)uu << 3)] = *(const short8*)(sb + ((size_t)uu << 3));
      }
    }
    __syncthreads();
    #pragma unroll
    for (int kt = 0; kt < 2; kt++){
      short8 a[4], b[4];
      #pragma unroll
      for (int i = 0; i < 4; i++)
        a[i] = *(short8*)&As[(((((wm<<2)+i) << 1) + kt) * 64 + lane) << 3];
      #pragma unroll
      for (int n = 0; n < 4; n++)
        b[n] = *(short8*)&Bs[(((kt << 3) + (wn<<2) + n) * 64 + lane) << 3];
      #pragma unroll
      for (int i = 0; i < 4; i++)
        #pragma unroll
        for (int n = 0; n < 4; n++)
          acc[i][n] = __builtin_amdgcn_mfma_f32_16x16x32_bf16(a[i], b[n], acc[i][n], 0, 0, 0);
    }
    __syncthreads();
  }

  int cq = lane >> 4, cn = lane & 15;
  #pragma unroll
  for (int i = 0; i < 4; i++){
    #pragma unroll
    for (int n = 0; n < 4; n++){
      int col = col0 + (wn<<6) + (n<<4) + cn;
      float bi = bias ? bias[col] : 0.0f;
      #pragma unroll
      for (int r = 0; r < 4; r++){
        int row = row0 + (wm<<6) + (i<<4) + (cq<<2) + r;
        float c = acc[i][n][r] + bi;
        if (act == 1) c = c > 0.0f ? c : 0.2f * c;
        if (resid) c += resid[(size_t)row * Nc + col];
        C[(size_t)row * Nc + col] = c;
      }
    }
  }
}

// ---------- vector GEMM (batched) — kept for P @ h2 (runtime B) ----------
__global__ __launch_bounds__(256) void gemm_k(
    const float* __restrict__ A, const float* __restrict__ W,
    const float* __restrict__ bias, const float* __restrict__ resid,
    float* __restrict__ C, int M, int Nc, int K, int act,
    size_t sA, size_t sW, size_t sC, size_t sR)
{
  __shared__ float As2[16][68];
  __shared__ float Bs2[16][68];
  const float* Ab = A + (size_t)blockIdx.z * sA;
  const float* Wb = W + (size_t)blockIdx.z * sW;
  const float* Rb = resid ? resid + (size_t)blockIdx.z * sR : nullptr;
  float*       Cb = C + (size_t)blockIdx.z * sC;

  int tid = threadIdx.x;
  int tx = tid & 15, ty = tid >> 4;
  int row0 = blockIdx.y << 6, col0 = blockIdx.x << 6;
  float acc[4][4] = {};
  int ra = tid >> 2, ca = (tid & 3) << 2;
  int rb = tid >> 4, cb = (tid & 15) << 2;

  for (int k0 = 0; k0 < K; k0 += 16){
    float4 av = *(const float4*)(Ab + (size_t)(row0 + ra) * K + k0 + ca);
    As2[ca+0][ra]=av.x; As2[ca+1][ra]=av.y; As2[ca+2][ra]=av.z; As2[ca+3][ra]=av.w;
    float4 wv = *(const float4*)(Wb + (size_t)(k0 + rb) * Nc + col0 + cb);
    Bs2[rb][cb+0]=wv.x; Bs2[rb][cb+1]=wv.y; Bs2[rb][cb+2]=wv.z; Bs2[rb][cb+3]=wv.w;
    __syncthreads();
    #pragma unroll
    for (int kk = 0; kk < 16; ++kk){
      float a[4], b[4];
      #pragma unroll
      for (int i = 0; i < 4; i++) a[i] = As2[kk][(ty<<2)+i];
      #pragma unroll
      for (int j = 0; j < 4; j++) b[j] = Bs2[kk][(tx<<2)+j];
      #pragma unroll
      for (int i = 0; i < 4; i++)
        #pragma unroll
        for (int j = 0; j < 4; j++)
          acc[i][j] = fmaf(a[i], b[j], acc[i][j]);
    }
    __syncthreads();
  }
  #pragma unroll
  for (int i = 0; i < 4; i++){
    int row = row0 + (ty<<2) + i;
    float4 rv;
    if (Rb) rv = *(const float4*)(Rb + (size_t)row * Nc + col0 + (tx<<2));
    float vals[4];
    #pragma unroll
    for (int j = 0; j < 4; j++){
      float c = acc[i][j];
      int col = col0 + (tx<<2) + j;
      if (bias)  c += bias[col];
      if (act == 1) c = c > 0.0f ? c : 0.2f * c;
      else if (act == 2) c = c > 0.0f ? c : expf(c) - 1.0f;
      if (Rb) c += (j==0?rv.x : j==1?rv.y : j==2?rv.z : rv.w);
      vals[j] = c;
    }
    *(float4*)(Cb + (size_t)row * Nc + col0 + (tx<<2)) = make_float4(vals[0],vals[1],vals[2],vals[3]);
  }
}

// ---------- tiled MHA attention (unchanged from R7) ----------
__global__ __launch_bounds__(256) void attn_tiled(
    const float* __restrict__ q, const float* __restrict__ k, const float* __restrict__ v,
    const int* __restrict__ mask, float* __restrict__ o, int Lq, int Lk)
{
  __shared__ float Qs[64][QT];
  __shared__ float KVs[128*64];
  __shared__ float Ls[QT][LSP];
  __shared__ float invs[QT];
  int tid = threadIdx.x;
  int q0 = blockIdx.x * QT, h = blockIdx.y, b = blockIdx.z;

  {
    int qr = tid >> 4, d4 = (tid & 15) << 2;
    float4 qq = *(const float4*)(q + ((size_t)(b*Lq + q0 + qr))*512 + h*64 + d4);
    Qs[d4+0][qr]=qq.x; Qs[d4+1][qr]=qq.y; Qs[d4+2][qr]=qq.z; Qs[d4+3][qr]=qq.w;
  }
  __syncthreads();

  for (int jt = 0; jt < Lk; jt += 128){
    int JT = min(128, Lk - jt);
    for (int x = tid; x < JT*16; x += 256){
      int jr = x >> 4, d4 = (x & 15) << 2;
      float4 kk = *(const float4*)(k + ((size_t)(b*Lk + jt + jr))*512 + h*64 + d4);
      KVs[(d4+0)*128 + jr]=kk.x; KVs[(d4+1)*128 + jr]=kk.y;
      KVs[(d4+2)*128 + jr]=kk.z; KVs[(d4+3)*128 + jr]=kk.w;
    }
    __syncthreads();
    int qi = (tid >> 5) << 1;
    int ji = (tid & 31) << 2;
    if (ji < JT){
      float a00=0,a01=0,a02=0,a03=0,a10=0,a11=0,a12=0,a13=0;
      #pragma unroll
      for (int d = 0; d < 64; d++){
        float x0 = Qs[d][qi], x1 = Qs[d][qi+1];
        const float4 kv = *(const float4*)&KVs[d*128 + ji];
        a00 = fmaf(x0, kv.x, a00); a01 = fmaf(x0, kv.y, a01);
        a02 = fmaf(x0, kv.z, a02); a03 = fmaf(x0, kv.w, a03);
        a10 = fmaf(x1, kv.x, a10); a11 = fmaf(x1, kv.y, a11);
        a12 = fmaf(x1, kv.z, a12); a13 = fmaf(x1, kv.w, a13);
      }
      const int4 m0 = *(const int4*)(mask + ((size_t)b*Lq + q0+qi  )*Lk + jt + ji);
      const int4 m1 = *(const int4*)(mask + ((size_t)b*Lq + q0+qi+1)*Lk + jt + ji);
      float4 e0, e1;
      e0.x = m0.x ? a00*0.125f : -1.0e9f;  e0.y = m0.y ? a01*0.125f : -1.0e9f;
      e0.z = m0.z ? a02*0.125f : -1.0e9f;  e0.w = m0.w ? a03*0.125f : -1.0e9f;
      e1.x = m1.x ? a10*0.125f : -1.0e9f;  e1.y = m1.y ? a11*0.125f : -1.0e9f;
      e1.z = m1.z ? a12*0.125f : -1.0e9f;  e1.w = m1.w ? a13*0.125f : -1.0e9f;
      *(float4*)&Ls[qi  ][jt+ji] = e0;
      *(float4*)&Ls[qi+1][jt+ji] = e1;
    }
    __syncthreads();
  }

  {
    int qq = tid >> 4, part = tid & 15;
    float mx = -3.0e38f;
    for (int j = part; j < Lk; j += 16) mx = fmaxf(mx, Ls[qq][j]);
    #pragma unroll
    for (int m = 1; m < 16; m <<= 1) mx = fmaxf(mx, __shfl_xor(mx, m, 16));
    float sum = 0.0f;
    for (int j = part; j < Lk; j += 16){
      float p = expf(Ls[qq][j] - mx);
      Ls[qq][j] = p; sum += p;
    }
    #pragma unroll
    for (int m = 1; m < 16; m <<= 1) sum += __shfl_xor(sum, m, 16);
    if (part == 0) invs[qq] = 1.0f / sum;
  }
  __syncthreads();

  int qq = tid >> 4, d4 = (tid & 15) << 2;
  float ax=0, ay=0, az=0, aw=0;
  for (int jt = 0; jt < Lk; jt += 128){
    int JT = min(128, Lk - jt);
    for (int x = tid; x < JT*16; x += 256){
      int jr = x >> 4, dd = (x & 15) << 2;
      *(float4*)&KVs[jr*64 + dd] =
        *(const float4*)(v + ((size_t)(b*Lk + jt + jr))*512 + h*64 + dd);
    }
    __syncthreads();
    #pragma unroll 4
    for (int jj = 0; jj < JT; jj++){
      float p = Ls[qq][jt + jj];
      const float4 vv = *(const float4*)&KVs[jj*64 + d4];
      ax = fmaf(p, vv.x, ax); ay = fmaf(p, vv.y, ay);
      az = fmaf(p, vv.z, az); aw = fmaf(p, vv.w, aw);
    }
    __syncthreads();
  }
  float inv = invs[qq];
  *(float4*)(o + ((size_t)(b*Lq + q0 + qq))*512 + h*64 + d4) =
    make_float4(ax*inv, ay*inv, az*inv, aw*inv);
}

// ---------- GAT scores ----------
__global__ __launch_bounds__(256) void gat1_scores(const float* __restrict__ hall,
    const float* __restrict__ gata, float* __restrict__ s1, float* __restrict__ s2)
{
  int gw = blockIdx.x * 4 + (threadIdx.x >> 6);
  int lane = threadIdx.x & 63;
  int h = gw >> 13;
  int r = gw & 8191;
  float v = hall[(size_t)r * D_ + h * 64 + lane];
  float p1 = v * gata[h * 128 + lane];
  float p2 = v * gata[h * 128 + 64 + lane];
  #pragma unroll
  for (int o = 32; o; o >>= 1){ p1 += __shfl_down(p1, o, 64); p2 += __shfl_down(p2, o, 64); }
  if (lane == 0){ s1[h * 8192 + r] = p1; s2[h * 8192 + r] = p2; }
}
__global__ __launch_bounds__(256) void gat2_scores(const float* __restrict__ h2,
    const float* __restrict__ gatoa, float* __restrict__ s1, float* __restrict__ s2)
{
  int r = blockIdx.x * 4 + (threadIdx.x >> 6);
  int lane = threadIdx.x & 63;
  float p1 = 0.0f, p2 = 0.0f;
  for (int c = lane; c < D_; c += 64){
    float v = h2[(size_t)r * D_ + c];
    p1 += v * gatoa[c];
    p2 += v * gatoa[D_ + c];
  }
  #pragma unroll
  for (int o = 32; o; o >>= 1){ p1 += __shfl_down(p1, o, 64); p2 += __shfl_down(p2, o, 64); }
  if (lane == 0){ s1[r] = p1; s2[r] = p2; }
}

// ---------- tiled GAT layer-1 attention (unchanged from R7) ----------
__global__ __launch_bounds__(256) void gat1_attn_tiled(const int* __restrict__ adj,
    const float* __restrict__ s1, const float* __restrict__ s2,
    const float* __restrict__ hall, float* __restrict__ xc)
{
  __shared__ float KVs[128*64];
  __shared__ float Ls[QT][LSP];
  __shared__ float invs[QT];
  int tid = threadIdx.x;
  int q0 = blockIdx.x * QT, h = blockIdx.y, b = blockIdx.z;
  int hb = h * 8192 + b * 512;

  {
    int qi = (tid >> 5) << 1;
    int ji = (tid & 31) << 2;
    float s10 = s1[hb + q0 + qi], s11 = s1[hb + q0 + qi + 1];
    for (int jt = 0; jt < 512; jt += 128){
      const float4 s2v = *(const float4*)(s2 + hb + jt + ji);
      const int4 m0 = *(const int4*)(adj + ((size_t)(b*512) + q0+qi  )*512 + jt + ji);
      const int4 m1 = *(const int4*)(adj + ((size_t)(b*512) + q0+qi+1)*512 + jt + ji);
      float4 e0, e1;
      float t;
      t = s10 + s2v.x; t = t>0?t:0.2f*t; e0.x = m0.x>0 ? t : -9.0e15f;
      t = s10 + s2v.y; t = t>0?t:0.2f*t; e0.y = m0.y>0 ? t : -9.0e15f;
      t = s10 + s2v.z; t = t>0?t:0.2f*t; e0.z = m0.z>0 ? t : -9.0e15f;
      t = s10 + s2v.w; t = t>0?t:0.2f*t; e0.w = m0.w>0 ? t : -9.0e15f;
      t = s11 + s2v.x; t = t>0?t:0.2f*t; e1.x = m1.x>0 ? t : -9.0e15f;
      t = s11 + s2v.y; t = t>0?t:0.2f*t; e1.y = m1.y>0 ? t : -9.0e15f;
      t = s11 + s2v.z; t = t>0?t:0.2f*t; e1.z = m1.z>0 ? t : -9.0e15f;
      t = s11 + s2v.w; t = t>0?t:0.2f*t; e1.w = m1.w>0 ? t : -9.0e15f;
      *(float4*)&Ls[qi  ][jt+ji] = e0;
      *(float4*)&Ls[qi+1][jt+ji] = e1;
    }
  }
  __syncthreads();

  {
    int qq = tid >> 4, part = tid & 15;
    float mx = -3.0e38f;
    for (int j = part; j < 512; j += 16) mx = fmaxf(mx, Ls[qq][j]);
    #pragma unroll
    for (int m = 1; m < 16; m <<= 1) mx = fmaxf(mx, __shfl_xor(mx, m, 16));
    float sum = 0.0f;
    for (int j = part; j < 512; j += 16){
      float p = expf(Ls[qq][j] - mx);
      Ls[qq][j] = p; sum += p;
    }
    #pragma unroll
    for (int m = 1; m < 16; m <<= 1) sum += __shfl_xor(sum, m, 16);
    if (part == 0) invs[qq] = 1.0f / sum;
  }
  __syncthreads();

  int qq = tid >> 4, d4 = (tid & 15) << 2;
  float ax=0, ay=0, az=0, aw=0;
  for (int jt = 0; jt < 512; jt += 128){
    for (int x = tid; x < 128*16; x += 256){
      int jr = x >> 4, dd = (x & 15) << 2;
      *(float4*)&KVs[jr*64 + dd] =
        *(const float4*)(hall + ((size_t)(b*512 + jt + jr))*512 + h*64 + dd);
    }
    __syncthreads();
    #pragma unroll 4
    for (int jj = 0; jj < 128; jj++){
      float p = Ls[qq][jt + jj];
      const float4 vv = *(const float4*)&KVs[jj*64 + d4];
      ax = fmaf(p, vv.x, ax); ay = fmaf(p, vv.y, ay);
      az = fmaf(p, vv.z, az); aw = fmaf(p, vv.w, aw);
    }
    __syncthreads();
  }
  float inv = invs[qq];
  ax*=inv; ay*=inv; az*=inv; aw*=inv;
  ax = ax>0?ax:expf(ax)-1.0f;  ay = ay>0?ay:expf(ay)-1.0f;
  az = az>0?az:expf(az)-1.0f;  aw = aw>0?aw:expf(aw)-1.0f;
  *(float4*)(xc + ((size_t)(b*512 + q0 + qq))*512 + h*64 + d4) = make_float4(ax,ay,az,aw);
}

// ---------- GAT output-layer probabilities ----------
__global__ __launch_bounds__(256) void gat2_prob(const int* __restrict__ adj,
    const float* __restrict__ s1, const float* __restrict__ s2, float* __restrict__ P)
{
  __shared__ float red[4];
  int r = blockIdx.x, tid = threadIdx.x;
  int b = r >> 9;
  float s1v = s1[r];
  float e0, e1;
  {
    float t = s1v + s2[b*512 + tid];       t = t>0?t:0.2f*t;
    e0 = adj[(size_t)r*512 + tid]       > 0 ? t : -9.0e15f;
    t = s1v + s2[b*512 + tid + 256];       t = t>0?t:0.2f*t;
    e1 = adj[(size_t)r*512 + tid + 256] > 0 ? t : -9.0e15f;
  }
  float mx = block_max(fmaxf(e0, e1), red);
  float p0 = expf(e0 - mx), p1 = expf(e1 - mx);
  float s = block_sum(p0 + p1, red);
  float inv = 1.0f / s;
  P[(size_t)r*512 + tid]       = p0 * inv;
  P[(size_t)r*512 + tid + 256] = p1 * inv;
}

// ---------- LayerNorm ----------
__global__ __launch_bounds__(256) void ln_k(const float* __restrict__ in,
    const float* __restrict__ g, const float* __restrict__ bta, float* __restrict__ out)
{
  __shared__ float red[4];
  int r = blockIdx.x, tid = threadIdx.x;
  const float* x = in + (size_t)r * D_;
  float v0 = x[tid], v1 = x[tid + 256];
  float mu = block_sum(v0 + v1, red) * (1.0f / 512.0f);
  float d0 = v0 - mu, d1 = v1 - mu;
  float var = block_sum(d0 * d0 + d1 * d1, red) * (1.0f / 512.0f);
  float inv = 1.0f / sqrtf(var + 1e-6f);
  out[(size_t)r * D_ + tid]       = d0 * inv * g[tid]       + bta[tid];
  out[(size_t)r * D_ + tid + 256] = d1 * inv * g[tid + 256] + bta[tid + 256];
}

// ---------- host-side MHA helper (MFMA projections; w = swizzled bf16 base, 4 DD mats) ----------
static void run_mha(hipStream_t st, const float* q_in, int Lq, const float* kv_in, int Lk,
                    const int* mask, const u16* w, const float* g, const float* bt,
                    float* qb, float* kb, float* vb, float* ob, float* tmp, float* out)
{
  dim3 blk(256);
  gemm_mfma<<<dim3(D_/128, (B_*Lq)/128), blk, 0, st>>>(q_in,  w + (size_t)0*DD, nullptr, nullptr, qb, D_, 0);
  gemm_mfma<<<dim3(D_/128, (B_*Lk)/128), blk, 0, st>>>(kv_in, w + (size_t)1*DD, nullptr, nullptr, kb, D_, 0);
  gemm_mfma<<<dim3(D_/128, (B_*Lk)/128), blk, 0, st>>>(kv_in, w + (size_t)2*DD, nullptr, nullptr, vb, D_, 0);
  attn_tiled<<<dim3(Lq/QT, NH_, B_), blk, 0, st>>>(qb, kb, vb, mask, ob, Lq, Lk);
  gemm_mfma<<<dim3(D_/128, (B_*Lq)/128), blk, 0, st>>>(ob, w + (size_t)3*DD, nullptr, q_in, tmp, D_, 0);
  ln_k<<<dim3(B_*Lq), blk, 0, st>>>(tmp, g, bt, out);
}

extern "C" void kernel_launch(void* const* d_in, const int* in_sizes, int n_in,
                              void* d_out, int out_size, void* d_ws, size_t ws_size,
                              hipStream_t stream) {
  (void)in_sizes; (void)n_in; (void)out_size; (void)ws_size;

  const float* xf    = (const float*)d_in[0];
  const int* adj_i   = (const int*)d_in[2];
  const int* adj_s   = (const int*)d_in[3];
  const int* adj_is  = (const int*)d_in[4];
  const int* adj_si  = (const int*)d_in[5];
  const float* intent= (const float*)d_in[6];
  const float* gatW  = (const float*)d_in[7];
  const float* gata  = (const float*)d_in[8];
  const float* gatoW = (const float*)d_in[9];
  const float* gatoa = (const float*)d_in[10];
  const float* mhaw  = (const float*)d_in[11];
  const float* lng   = (const float*)d_in[12];
  const float* lnb   = (const float*)d_in[13];
  const float* linW1 = (const float*)d_in[14];
  const float* linb1 = (const float*)d_in[15];
  const float* linW2 = (const float*)d_in[16];
  const float* linb2 = (const float*)d_in[17];

  float* out0 = (float*)d_out;                   // slot_out      [B,N,D]
  float* out1 = out0 + BND;                      // slot_logits   [B,N,OUT]
  float* out2 = out1 + (size_t)B_*N_*OUT_;       // slot_graph_out[B,N,D]

  // ---- workspace carve (~129 MB) ----
  float* Q    = (float*)d_ws;      // BND x6
  float* K    = Q   + BND;
  float* V    = K   + BND;
  float* O    = V   + BND;
  float* TMP  = O   + BND;
  float* HB1  = TMP + BND;
  float* ha0  = HB1 + BND;         // BID x9
  float* ha1  = ha0 + BID;
  float* ta   = ha1 + BID;
  float* tb   = ta  + BID;
  float* sqa  = tb  + BID;
  float* ska  = sqa + BID;
  float* sva  = ska + BID;
  float* soa  = sva + BID;
  float* stmp = soa + BID;
  float* s1   = stmp+ BID;         // 65536 x2
  float* s2   = s1  + 65536;
  float* s1o  = s2  + 65536;       // 8192 x2
  float* s2o  = s1o + 8192;
  u16* Wm  = (u16*)(s2o + 8192);   // 32*DD bf16 (all mhaw mats, swizzled)
  u16* Wg  = Wm  + (size_t)32*DD;  // gat Wcat swizzled
  u16* Wgo = Wg  + DD;             // gat_out_W swizzled
  u16* W1s = Wgo + DD;             // lin_W1 swizzled
  u16* W2s = W1s + DD;             // lin_W2 swizzled (512x128 -> DD/4)

  dim3 blk(256);

  // ---- weight prep (swizzle to MFMA B-fragment order) ----
  swz_k<<<dim3(128, 32), blk, 0, stream>>>(mhaw,  Wm,  D_,   DD, DD);
  swz_gatW_k<<<128, blk, 0, stream>>>(gatW, Wg);
  swz_k<<<dim3(128, 1), blk, 0, stream>>>(gatoW, Wgo, D_,   0, 0);
  swz_k<<<dim3(128, 1), blk, 0, stream>>>(linW1, W1s, D_,   0, 0);
  swz_k<<<dim3(32,  1), blk, 0, stream>>>(linW2, W2s, OUT_, 0, 0);

  // ================= MHA stack =================
  bcast_k<<<BID/256, blk, 0, stream>>>(intent, ha0, BID);

  // ---- layer 0 (h_b = xf, h_a = ha0) ----
  run_mha(stream, ha0, NI_, ha0, NI_, adj_i,  Wm +  (size_t)0*DD, lng + 0*D_, lnb + 0*D_,
          sqa, ska, sva, soa, stmp, ta);                                   // a2a -> ta
  run_mha(stream, ha0, NI_, xf,  N_,  adj_si, Wm + (size_t)12*DD, lng + 3*D_, lnb + 3*D_,
          sqa, K, V, soa, stmp, tb);                                       // b2a -> tb
  add_relu_k<<<BID/256, blk, 0, stream>>>(ta, tb, ha1, BID);               // h_a1
  run_mha(stream, xf, N_, xf, N_, adj_s,  Wm +  (size_t)4*DD, lng + 1*D_, lnb + 1*D_,
          Q, K, V, O, TMP, HB1);                                           // b2b -> HB1
  run_mha(stream, xf, N_, ha0, NI_, adj_is, Wm + (size_t)8*DD, lng + 2*D_, lnb + 2*D_,
          Q, ska, sva, O, TMP, Q);                                         // a2b -> Q
  add_relu_ip_k<<<BND/256, blk, 0, stream>>>(HB1, Q, BND);                 // h_b1

  // ---- layer 1 (h_b = HB1, h_a = ha1); a2a/b2a dead ----
  run_mha(stream, HB1, N_, HB1, N_, adj_s,  Wm + (size_t)20*DD, lng + 5*D_, lnb + 5*D_,
          Q, K, V, O, TMP, K);                                             // b2b -> K
  run_mha(stream, HB1, N_, ha1, NI_, adj_is, Wm + (size_t)24*DD, lng + 6*D_, lnb + 6*D_,
          Q, ska, sva, O, TMP, Q);                                         // a2b -> Q
  add_relu_ip_k<<<BND/256, blk, 0, stream>>>(K, Q, BND);                   // h_b2 in K

  // ---- slot_out = x + h_b2 ----
  add_k<<<BND/256, blk, 0, stream>>>(xf, K, out0, BND);
  // ---- logits ----
  gemm_mfma<<<dim3(D_/128, (B_*N_)/128), blk, 0, stream>>>(out0, W1s, linb1, nullptr, Q, D_, 1);
  gemm_mfma<<<dim3(OUT_/128, (B_*N_)/128), blk, 0, stream>>>(Q, W2s, linb2, nullptr, out1, OUT_, 0);

  // ================= GAT branch =================
  gemm_mfma<<<dim3(D_/128, (B_*N_)/128), blk, 0, stream>>>(xf, Wg, nullptr, nullptr, Q /*h_all*/, D_, 0);
  gat1_scores<<<(H_*B_*N_)/4, blk, 0, stream>>>(Q, gata, s1, s2);
  gat1_attn_tiled<<<dim3(N_/QT, H_, B_), blk, 0, stream>>>(adj_s, s1, s2, Q, K /*xc*/);
  gemm_mfma<<<dim3(D_/128, (B_*N_)/128), blk, 0, stream>>>(K, Wgo, nullptr, nullptr, V /*h2*/, D_, 0);
  gat2_scores<<<(B_*N_)/4, blk, 0, stream>>>(V, gatoa, s1o, s2o);
  gat2_prob<<<B_*N_, blk, 0, stream>>>(adj_s, s1o, s2o, HB1 /*P*/);
  // out2 = elu(P @ h2) + x   (batched over B, runtime B-matrix -> vector GEMM)
  gemm_k<<<dim3(D_/64, N_/64, B_), blk, 0, stream>>>(HB1, V, nullptr, xf, out2, N_, D_, D_, 2,
                                                     (size_t)N_*N_, (size_t)N_*D_, (size_t)N_*D_, (size_t)N_*D_);
}